// Round 1
// baseline (1293.888 us; speedup 1.0000x reference)
//
#include <hip/hip_runtime.h>
#include <hip/hip_bf16.h>
#include <math.h>

#define N_NODES 100000
#define N_EDGES 1600000
#define NF 128
#define NC 40

#define SCAN_CHUNK 512
#define SCAN_BLOCKS ((N_NODES + SCAN_CHUNK - 1) / SCAN_CHUNK)  // 196

// ---------------- CSR build ----------------

__global__ void k_degree(const int* __restrict__ dst, unsigned* __restrict__ cnt) {
    int e = blockIdx.x * 256 + threadIdx.x;
    if (e < N_EDGES) atomicAdd(&cnt[dst[e]], 1u);
}

__global__ void k_scanA(const unsigned* __restrict__ cnt, unsigned* __restrict__ bsum) {
    __shared__ unsigned red[256];
    int t = threadIdx.x;
    int i0 = blockIdx.x * SCAN_CHUNK + 2 * t;
    unsigned s = 0;
    if (i0 < N_NODES) s += cnt[i0];
    if (i0 + 1 < N_NODES) s += cnt[i0 + 1];
    red[t] = s; __syncthreads();
    for (int off = 128; off; off >>= 1) {
        if (t < off) red[t] += red[t + off];
        __syncthreads();
    }
    if (t == 0) bsum[blockIdx.x] = red[0];
}

__global__ void k_scanB(unsigned* bsum, unsigned* rowptr) {
    __shared__ unsigned tmp[256];
    int t = threadIdx.x;
    unsigned v = (t < SCAN_BLOCKS) ? bsum[t] : 0;
    tmp[t] = v; __syncthreads();
    for (int off = 1; off < 256; off <<= 1) {
        unsigned add = (t >= off) ? tmp[t - off] : 0;
        __syncthreads();
        tmp[t] += add;
        __syncthreads();
    }
    unsigned incl = tmp[t];
    if (t < SCAN_BLOCKS) bsum[t] = incl - v;   // exclusive
    if (t == 255) rowptr[N_NODES] = incl;      // total == N_EDGES
}

__global__ void k_scanC(const unsigned* __restrict__ cnt, const unsigned* __restrict__ bsum,
                        unsigned* __restrict__ rowptr) {
    __shared__ unsigned tmp[256];
    int t = threadIdx.x;
    int i0 = blockIdx.x * SCAN_CHUNK + 2 * t;
    unsigned c0 = (i0 < N_NODES) ? cnt[i0] : 0;
    unsigned c1 = (i0 + 1 < N_NODES) ? cnt[i0 + 1] : 0;
    unsigned s = c0 + c1;
    tmp[t] = s; __syncthreads();
    for (int off = 1; off < 256; off <<= 1) {
        unsigned add = (t >= off) ? tmp[t - off] : 0;
        __syncthreads();
        tmp[t] += add;
        __syncthreads();
    }
    unsigned excl = tmp[t] - s;
    unsigned bb = bsum[blockIdx.x];
    if (i0 < N_NODES) rowptr[i0] = bb + excl;
    if (i0 + 1 < N_NODES) rowptr[i0 + 1] = bb + excl + c0;
}

__global__ void k_scatter(const int* __restrict__ src, const int* __restrict__ dst,
                          unsigned* __restrict__ cursor, unsigned* __restrict__ srcs) {
    int e = blockIdx.x * 256 + threadIdx.x;
    if (e < N_EDGES) {
        unsigned p = atomicAdd(&cursor[dst[e]], 1u);
        srcs[p] = (unsigned)src[e];
    }
}

// ---------------- mean aggregation (one wave per node) ----------------

__global__ __launch_bounds__(256) void k_aggregate(const float* __restrict__ h,
                                                   const unsigned* __restrict__ rowptr,
                                                   const unsigned* __restrict__ srcs,
                                                   float* __restrict__ agg) {
    int wave = threadIdx.x >> 6;
    int lane = threadIdx.x & 63;
    int node = blockIdx.x * 4 + wave;
    if (node >= N_NODES) return;
    unsigned b = rowptr[node], e = rowptr[node + 1];
    float a0 = 0.f, a1 = 0.f, b0 = 0.f, b1 = 0.f;
    unsigned i = b;
    for (; i + 2 <= e; i += 2) {
        unsigned s0 = srcs[i], s1 = srcs[i + 1];
        const float* p0 = h + (size_t)s0 * NF;
        const float* p1 = h + (size_t)s1 * NF;
        a0 += p0[lane]; a1 += p0[lane + 64];
        b0 += p1[lane]; b1 += p1[lane + 64];
    }
    if (i < e) {
        unsigned s = srcs[i];
        const float* p = h + (size_t)s * NF;
        a0 += p[lane]; a1 += p[lane + 64];
    }
    float sc = 1.f / fmaxf((float)(e - b), 1.f);
    agg[(size_t)node * NF + lane] = (a0 + b0) * sc;
    agg[(size_t)node * NF + 64 + lane] = (a1 + b1) * sc;
}

// ---------------- fused GEMM: out = act(A1@W1.T [+ A2@W2.T] + bias) ----------------
// 32 rows/block, 256 threads: thread (c = t&63, g = t>>6) computes rows g*8..g*8+7,
// cols c and c+64.

template <int HAS2, int RELU>
__global__ __launch_bounds__(256) void k_gemm128(const float* __restrict__ A1,
                                                 const float* __restrict__ W1,
                                                 const float* __restrict__ A2,
                                                 const float* __restrict__ W2,
                                                 const float* __restrict__ bias,
                                                 float* __restrict__ out, int nrows) {
    __shared__ float4 As[32][32];  // 32 rows x 128 floats
    const int t = threadIdx.x;
    const int c = t & 63;
    const int g = t >> 6;
    const int row0 = blockIdx.x * 32;
    float acc0[8], acc1[8];
#pragma unroll
    for (int i = 0; i < 8; ++i) { acc0[i] = 0.f; acc1[i] = 0.f; }

    const int npass = HAS2 ? 2 : 1;
    for (int pass = 0; pass < npass; ++pass) {
        const float* A = pass ? A2 : A1;
        const float* W = pass ? W2 : W1;
        if (pass) __syncthreads();
        // stage 32 rows (1024 float4, 4 per thread)
#pragma unroll
        for (int i = 0; i < 4; ++i) {
            int idx = t + i * 256;
            int r = idx >> 5, q = idx & 31;
            int gr = row0 + r;
            As[r][q] = (gr < nrows) ? ((const float4*)(A + (size_t)gr * NF))[q]
                                    : make_float4(0.f, 0.f, 0.f, 0.f);
        }
        __syncthreads();
        const float4* w0 = (const float4*)(W + (size_t)c * NF);
        const float4* w1 = (const float4*)(W + (size_t)(c + 64) * NF);
        for (int k4 = 0; k4 < 32; ++k4) {
            float4 wa = w0[k4];
            float4 wb = w1[k4];
#pragma unroll
            for (int i = 0; i < 8; ++i) {
                float4 av = As[g * 8 + i][k4];
                acc0[i] += av.x * wa.x + av.y * wa.y + av.z * wa.z + av.w * wa.w;
                acc1[i] += av.x * wb.x + av.y * wb.y + av.z * wb.z + av.w * wb.w;
            }
        }
    }
    float ba = bias[c], bb = bias[c + 64];
#pragma unroll
    for (int i = 0; i < 8; ++i) {
        int r = row0 + g * 8 + i;
        if (r < nrows) {
            float v0 = acc0[i] + ba;
            float v1 = acc1[i] + bb;
            if (RELU) { v0 = fmaxf(v0, 0.f); v1 = fmaxf(v1, 0.f); }
            out[(size_t)r * NF + c] = v0;
            out[(size_t)r * NF + 64 + c] = v1;
        }
    }
}

// ---------------- post-linear + log_softmax (one wave per node) ----------------

__global__ __launch_bounds__(256) void k_post(const float* __restrict__ h,
                                              const float* __restrict__ Wp,
                                              const float* __restrict__ bp,
                                              float* __restrict__ out) {
    int wave = threadIdx.x >> 6, lane = threadIdx.x & 63;
    int node = blockIdx.x * 4 + wave;
    if (node >= N_NODES) return;
    const float4* hp = (const float4*)(h + (size_t)node * NF);
    float logit = -1e30f;
    if (lane < NC) {
        const float4* wp = (const float4*)(Wp + (size_t)lane * NF);
        float d = 0.f;
#pragma unroll
        for (int k = 0; k < 32; ++k) {
            float4 a = hp[k], w = wp[k];
            d += a.x * w.x + a.y * w.y + a.z * w.z + a.w * w.w;
        }
        logit = d + bp[lane];
    }
    float m = logit;
    for (int off = 32; off; off >>= 1) m = fmaxf(m, __shfl_xor(m, off, 64));
    float p = (lane < NC) ? expf(logit - m) : 0.f;
    float s = p;
    for (int off = 32; off; off >>= 1) s += __shfl_xor(s, off, 64);
    if (lane < NC) out[(size_t)node * NC + lane] = logit - m - logf(s);
}

// ---------------- launch ----------------

extern "C" void kernel_launch(void* const* d_in, const int* in_sizes, int n_in,
                              void* d_out, int out_size, void* d_ws, size_t ws_size,
                              hipStream_t stream) {
    const float* x      = (const float*)d_in[0];
    const int*   ei     = (const int*)d_in[1];
    const float* W_pre  = (const float*)d_in[2];
    const float* b_pre  = (const float*)d_in[3];
    const float* Wl0    = (const float*)d_in[4];
    const float* bl0    = (const float*)d_in[5];
    const float* Wr0    = (const float*)d_in[6];
    const float* Wl1    = (const float*)d_in[7];
    const float* bl1    = (const float*)d_in[8];
    const float* Wr1    = (const float*)d_in[9];
    const float* W_post = (const float*)d_in[10];
    const float* b_post = (const float*)d_in[11];
    const int* src = ei;
    const int* dst = ei + N_EDGES;

    char* w = (char*)d_ws;
    float* h0  = (float*)w; w += (size_t)N_NODES * NF * 4;   // 51.2 MB (reused for h2)
    float* h1  = (float*)w; w += (size_t)N_NODES * NF * 4;
    float* agg = (float*)w; w += (size_t)N_NODES * NF * 4;
    unsigned* cnt    = (unsigned*)w; w += (size_t)(N_NODES + 32) * 4;
    unsigned* rowptr = (unsigned*)w; w += (size_t)(N_NODES + 32) * 4;
    unsigned* cursor = (unsigned*)w; w += (size_t)(N_NODES + 32) * 4;
    unsigned* bsum   = (unsigned*)w; w += 256 * 4;
    unsigned* srcs   = (unsigned*)w; w += (size_t)N_EDGES * 4;
    float* h2 = h0;

    float* outp = (float*)d_out;

    // CSR build (per call; deterministic work)
    hipMemsetAsync(cnt, 0, (size_t)N_NODES * 4, stream);
    k_degree<<<(N_EDGES + 255) / 256, 256, 0, stream>>>(dst, cnt);
    k_scanA<<<SCAN_BLOCKS, 256, 0, stream>>>(cnt, bsum);
    k_scanB<<<1, 256, 0, stream>>>(bsum, rowptr);
    k_scanC<<<SCAN_BLOCKS, 256, 0, stream>>>(cnt, bsum, rowptr);
    hipMemcpyAsync(cursor, rowptr, (size_t)N_NODES * 4, hipMemcpyDeviceToDevice, stream);
    k_scatter<<<(N_EDGES + 255) / 256, 256, 0, stream>>>(src, dst, cursor, srcs);

    const int gemm_grid = (N_NODES + 31) / 32;
    const int node_grid = (N_NODES + 3) / 4;

    // pre-linear
    k_gemm128<0, 0><<<gemm_grid, 256, 0, stream>>>(x, W_pre, nullptr, nullptr, b_pre, h0, N_NODES);
    // conv0
    k_aggregate<<<node_grid, 256, 0, stream>>>(h0, rowptr, srcs, agg);
    k_gemm128<1, 1><<<gemm_grid, 256, 0, stream>>>(agg, Wl0, h0, Wr0, bl0, h1, N_NODES);
    // conv1
    k_aggregate<<<node_grid, 256, 0, stream>>>(h1, rowptr, srcs, agg);
    k_gemm128<1, 1><<<gemm_grid, 256, 0, stream>>>(agg, Wl1, h1, Wr1, bl1, h2, N_NODES);
    // post + log_softmax
    k_post<<<node_grid, 256, 0, stream>>>(h2, W_post, b_post, outp);
}

// Round 2
// 1259.875 us; speedup vs baseline: 1.0270x; 1.0270x over previous
//
#include <hip/hip_runtime.h>
#include <hip/hip_bf16.h>
#include <math.h>

#define N_NODES 100000
#define N_EDGES 1600000
#define NF 128
#define NC 40

#define SCAN_CHUNK 512
#define SCAN_BLOCKS ((N_NODES + SCAN_CHUNK - 1) / SCAN_CHUNK)  // 196

// ---------------- CSR build ----------------

__global__ void k_degree(const int* __restrict__ dst, unsigned* __restrict__ cnt) {
    int e = blockIdx.x * 256 + threadIdx.x;
    if (e < N_EDGES) atomicAdd(&cnt[dst[e]], 1u);
}

__global__ void k_scanA(const unsigned* __restrict__ cnt, unsigned* __restrict__ bsum) {
    __shared__ unsigned red[256];
    int t = threadIdx.x;
    int i0 = blockIdx.x * SCAN_CHUNK + 2 * t;
    unsigned s = 0;
    if (i0 < N_NODES) s += cnt[i0];
    if (i0 + 1 < N_NODES) s += cnt[i0 + 1];
    red[t] = s; __syncthreads();
    for (int off = 128; off; off >>= 1) {
        if (t < off) red[t] += red[t + off];
        __syncthreads();
    }
    if (t == 0) bsum[blockIdx.x] = red[0];
}

__global__ void k_scanB(unsigned* bsum, unsigned* rowptr) {
    __shared__ unsigned tmp[256];
    int t = threadIdx.x;
    unsigned v = (t < SCAN_BLOCKS) ? bsum[t] : 0;
    tmp[t] = v; __syncthreads();
    for (int off = 1; off < 256; off <<= 1) {
        unsigned add = (t >= off) ? tmp[t - off] : 0;
        __syncthreads();
        tmp[t] += add;
        __syncthreads();
    }
    unsigned incl = tmp[t];
    if (t < SCAN_BLOCKS) bsum[t] = incl - v;   // exclusive
    if (t == 255) rowptr[N_NODES] = incl;      // total == N_EDGES
}

__global__ void k_scanC(const unsigned* __restrict__ cnt, const unsigned* __restrict__ bsum,
                        unsigned* __restrict__ rowptr) {
    __shared__ unsigned tmp[256];
    int t = threadIdx.x;
    int i0 = blockIdx.x * SCAN_CHUNK + 2 * t;
    unsigned c0 = (i0 < N_NODES) ? cnt[i0] : 0;
    unsigned c1 = (i0 + 1 < N_NODES) ? cnt[i0 + 1] : 0;
    unsigned s = c0 + c1;
    tmp[t] = s; __syncthreads();
    for (int off = 1; off < 256; off <<= 1) {
        unsigned add = (t >= off) ? tmp[t - off] : 0;
        __syncthreads();
        tmp[t] += add;
        __syncthreads();
    }
    unsigned excl = tmp[t] - s;
    unsigned bb = bsum[blockIdx.x];
    if (i0 < N_NODES) rowptr[i0] = bb + excl;
    if (i0 + 1 < N_NODES) rowptr[i0 + 1] = bb + excl + c0;
}

__global__ void k_scatter(const int* __restrict__ src, const int* __restrict__ dst,
                          unsigned* __restrict__ cursor, unsigned* __restrict__ srcs) {
    int e = blockIdx.x * 256 + threadIdx.x;
    if (e < N_EDGES) {
        unsigned p = atomicAdd(&cursor[dst[e]], 1u);
        srcs[p] = (unsigned)src[e];
    }
}

// ---------------- mean aggregation (one wave per node) ----------------

__global__ __launch_bounds__(256) void k_aggregate(const float* __restrict__ h,
                                                   const unsigned* __restrict__ rowptr,
                                                   const unsigned* __restrict__ srcs,
                                                   float* __restrict__ agg) {
    int wave = threadIdx.x >> 6;
    int lane = threadIdx.x & 63;
    int node = blockIdx.x * 4 + wave;
    if (node >= N_NODES) return;
    unsigned b = rowptr[node], e = rowptr[node + 1];
    float a0 = 0.f, a1 = 0.f, b0 = 0.f, b1 = 0.f;
    unsigned i = b;
    for (; i + 2 <= e; i += 2) {
        unsigned s0 = srcs[i], s1 = srcs[i + 1];
        const float* p0 = h + (size_t)s0 * NF;
        const float* p1 = h + (size_t)s1 * NF;
        a0 += p0[lane]; a1 += p0[lane + 64];
        b0 += p1[lane]; b1 += p1[lane + 64];
    }
    if (i < e) {
        unsigned s = srcs[i];
        const float* p = h + (size_t)s * NF;
        a0 += p[lane]; a1 += p[lane + 64];
    }
    float sc = 1.f / fmaxf((float)(e - b), 1.f);
    agg[(size_t)node * NF + lane] = (a0 + b0) * sc;
    agg[(size_t)node * NF + 64 + lane] = (a1 + b1) * sc;
}

// ---------------- fused GEMM: out = act(A1@W1.T [+ A2@W2.T] + bias) ----------------
// 32 rows/block, 256 threads: thread (c = t&63, g = t>>6) computes rows g*8..g*8+7,
// cols c and c+64.

template <int HAS2, int RELU>
__global__ __launch_bounds__(256) void k_gemm128(const float* __restrict__ A1,
                                                 const float* __restrict__ W1,
                                                 const float* __restrict__ A2,
                                                 const float* __restrict__ W2,
                                                 const float* __restrict__ bias,
                                                 float* __restrict__ out, int nrows) {
    __shared__ float4 As[32][32];  // 32 rows x 128 floats
    const int t = threadIdx.x;
    const int c = t & 63;
    const int g = t >> 6;
    const int row0 = blockIdx.x * 32;
    float acc0[8], acc1[8];
#pragma unroll
    for (int i = 0; i < 8; ++i) { acc0[i] = 0.f; acc1[i] = 0.f; }

    const int npass = HAS2 ? 2 : 1;
    for (int pass = 0; pass < npass; ++pass) {
        const float* A = pass ? A2 : A1;
        const float* W = pass ? W2 : W1;
        if (pass) __syncthreads();
        // stage 32 rows (1024 float4, 4 per thread)
#pragma unroll
        for (int i = 0; i < 4; ++i) {
            int idx = t + i * 256;
            int r = idx >> 5, q = idx & 31;
            int gr = row0 + r;
            As[r][q] = (gr < nrows) ? ((const float4*)(A + (size_t)gr * NF))[q]
                                    : make_float4(0.f, 0.f, 0.f, 0.f);
        }
        __syncthreads();
        const float4* w0 = (const float4*)(W + (size_t)c * NF);
        const float4* w1 = (const float4*)(W + (size_t)(c + 64) * NF);
        for (int k4 = 0; k4 < 32; ++k4) {
            float4 wa = w0[k4];
            float4 wb = w1[k4];
#pragma unroll
            for (int i = 0; i < 8; ++i) {
                float4 av = As[g * 8 + i][k4];
                acc0[i] += av.x * wa.x + av.y * wa.y + av.z * wa.z + av.w * wa.w;
                acc1[i] += av.x * wb.x + av.y * wb.y + av.z * wb.z + av.w * wb.w;
            }
        }
    }
    float ba = bias[c], bb = bias[c + 64];
#pragma unroll
    for (int i = 0; i < 8; ++i) {
        int r = row0 + g * 8 + i;
        if (r < nrows) {
            float v0 = acc0[i] + ba;
            float v1 = acc1[i] + bb;
            if (RELU) { v0 = fmaxf(v0, 0.f); v1 = fmaxf(v1, 0.f); }
            out[(size_t)r * NF + c] = v0;
            out[(size_t)r * NF + 64 + c] = v1;
        }
    }
}

// ---------------- post-linear + log_softmax, blocked GEMM style ----------------
// 32 nodes/block, 256 threads. Thread (c = t&63, g = t>>6) computes rows
// g*8..g*8+7, class c (active for c < 40). Log-softmax fused: wave g owns all
// 40 classes of its 8 rows across lanes -> shuffle reduce.

__global__ __launch_bounds__(256) void k_post(const float* __restrict__ h,
                                              const float* __restrict__ Wp,
                                              const float* __restrict__ bp,
                                              float* __restrict__ out) {
    __shared__ float4 As[32][32];  // 32 rows x 128 floats
    const int t = threadIdx.x;
    const int c = t & 63;
    const int g = t >> 6;
    const int row0 = blockIdx.x * 32;
#pragma unroll
    for (int i = 0; i < 4; ++i) {
        int idx = t + i * 256;
        int r = idx >> 5, q = idx & 31;
        int gr = row0 + r;
        As[r][q] = (gr < N_NODES) ? ((const float4*)(h + (size_t)gr * NF))[q]
                                  : make_float4(0.f, 0.f, 0.f, 0.f);
    }
    __syncthreads();
    float acc[8];
    if (c < NC) {
        const float4* wp = (const float4*)(Wp + (size_t)c * NF);
        float bb = bp[c];
#pragma unroll
        for (int i = 0; i < 8; ++i) acc[i] = bb;
        for (int k4 = 0; k4 < 32; ++k4) {
            float4 wa = wp[k4];
#pragma unroll
            for (int i = 0; i < 8; ++i) {
                float4 av = As[g * 8 + i][k4];
                acc[i] += av.x * wa.x + av.y * wa.y + av.z * wa.z + av.w * wa.w;
            }
        }
    } else {
#pragma unroll
        for (int i = 0; i < 8; ++i) acc[i] = -INFINITY;
    }
#pragma unroll
    for (int i = 0; i < 8; ++i) {
        float v = acc[i];
        float m = v;
        for (int off = 32; off; off >>= 1) m = fmaxf(m, __shfl_xor(m, off, 64));
        float p = (c < NC) ? expf(v - m) : 0.f;
        float s = p;
        for (int off = 32; off; off >>= 1) s += __shfl_xor(s, off, 64);
        if (c < NC) {
            int r = row0 + g * 8 + i;
            if (r < N_NODES) out[(size_t)r * NC + c] = v - m - logf(s);
        }
    }
}

// ---------------- launch ----------------

extern "C" void kernel_launch(void* const* d_in, const int* in_sizes, int n_in,
                              void* d_out, int out_size, void* d_ws, size_t ws_size,
                              hipStream_t stream) {
    const float* x      = (const float*)d_in[0];
    const int*   ei     = (const int*)d_in[1];
    const float* W_pre  = (const float*)d_in[2];
    const float* b_pre  = (const float*)d_in[3];
    const float* Wl0    = (const float*)d_in[4];
    const float* bl0    = (const float*)d_in[5];
    const float* Wr0    = (const float*)d_in[6];
    const float* Wl1    = (const float*)d_in[7];
    const float* bl1    = (const float*)d_in[8];
    const float* Wr1    = (const float*)d_in[9];
    const float* W_post = (const float*)d_in[10];
    const float* b_post = (const float*)d_in[11];
    const int* src = ei;
    const int* dst = ei + N_EDGES;

    char* w = (char*)d_ws;
    float* h0  = (float*)w; w += (size_t)N_NODES * NF * 4;   // 51.2 MB (reused for h2)
    float* h1  = (float*)w; w += (size_t)N_NODES * NF * 4;
    float* agg = (float*)w; w += (size_t)N_NODES * NF * 4;
    unsigned* cnt    = (unsigned*)w; w += (size_t)(N_NODES + 32) * 4;
    unsigned* rowptr = (unsigned*)w; w += (size_t)(N_NODES + 32) * 4;
    unsigned* cursor = (unsigned*)w; w += (size_t)(N_NODES + 32) * 4;
    unsigned* bsum   = (unsigned*)w; w += 256 * 4;
    unsigned* srcs   = (unsigned*)w; w += (size_t)N_EDGES * 4;
    float* h2 = h0;

    float* outp = (float*)d_out;

    // CSR build (per call; deterministic work)
    hipMemsetAsync(cnt, 0, (size_t)N_NODES * 4, stream);
    k_degree<<<(N_EDGES + 255) / 256, 256, 0, stream>>>(dst, cnt);
    k_scanA<<<SCAN_BLOCKS, 256, 0, stream>>>(cnt, bsum);
    k_scanB<<<1, 256, 0, stream>>>(bsum, rowptr);
    k_scanC<<<SCAN_BLOCKS, 256, 0, stream>>>(cnt, bsum, rowptr);
    hipMemcpyAsync(cursor, rowptr, (size_t)N_NODES * 4, hipMemcpyDeviceToDevice, stream);
    k_scatter<<<(N_EDGES + 255) / 256, 256, 0, stream>>>(src, dst, cursor, srcs);

    const int gemm_grid = (N_NODES + 31) / 32;
    const int node_grid = (N_NODES + 3) / 4;

    // pre-linear
    k_gemm128<0, 0><<<gemm_grid, 256, 0, stream>>>(x, W_pre, nullptr, nullptr, b_pre, h0, N_NODES);
    // conv0
    k_aggregate<<<node_grid, 256, 0, stream>>>(h0, rowptr, srcs, agg);
    k_gemm128<1, 1><<<gemm_grid, 256, 0, stream>>>(agg, Wl0, h0, Wr0, bl0, h1, N_NODES);
    // conv1
    k_aggregate<<<node_grid, 256, 0, stream>>>(h1, rowptr, srcs, agg);
    k_gemm128<1, 1><<<gemm_grid, 256, 0, stream>>>(agg, Wl1, h1, Wr1, bl1, h2, N_NODES);
    // post + log_softmax
    k_post<<<node_grid, 256, 0, stream>>>(h2, W_post, b_post, outp);
}

// Round 3
// 1017.997 us; speedup vs baseline: 1.2710x; 1.2376x over previous
//
#include <hip/hip_runtime.h>
#include <hip/hip_bf16.h>
#include <math.h>

#define N_NODES 100000
#define N_EDGES 1600000
#define NF 128
#define NC 40

#define SCAN_CHUNK 512
#define SCAN_BLOCKS ((N_NODES + SCAN_CHUNK - 1) / SCAN_CHUNK)  // 196

// ---------------- CSR build ----------------

__global__ void k_degree(const int* __restrict__ dst, unsigned* __restrict__ cnt) {
    int e = blockIdx.x * 256 + threadIdx.x;
    if (e < N_EDGES) atomicAdd(&cnt[dst[e]], 1u);
}

__global__ void k_scanA(const unsigned* __restrict__ cnt, unsigned* __restrict__ bsum) {
    __shared__ unsigned red[256];
    int t = threadIdx.x;
    int i0 = blockIdx.x * SCAN_CHUNK + 2 * t;
    unsigned s = 0;
    if (i0 < N_NODES) s += cnt[i0];
    if (i0 + 1 < N_NODES) s += cnt[i0 + 1];
    red[t] = s; __syncthreads();
    for (int off = 128; off; off >>= 1) {
        if (t < off) red[t] += red[t + off];
        __syncthreads();
    }
    if (t == 0) bsum[blockIdx.x] = red[0];
}

__global__ void k_scanB(unsigned* bsum, unsigned* rowptr) {
    __shared__ unsigned tmp[256];
    int t = threadIdx.x;
    unsigned v = (t < SCAN_BLOCKS) ? bsum[t] : 0;
    tmp[t] = v; __syncthreads();
    for (int off = 1; off < 256; off <<= 1) {
        unsigned add = (t >= off) ? tmp[t - off] : 0;
        __syncthreads();
        tmp[t] += add;
        __syncthreads();
    }
    unsigned incl = tmp[t];
    if (t < SCAN_BLOCKS) bsum[t] = incl - v;   // exclusive
    if (t == 255) rowptr[N_NODES] = incl;      // total == N_EDGES
}

__global__ void k_scanC(const unsigned* __restrict__ cnt, const unsigned* __restrict__ bsum,
                        unsigned* __restrict__ rowptr) {
    __shared__ unsigned tmp[256];
    int t = threadIdx.x;
    int i0 = blockIdx.x * SCAN_CHUNK + 2 * t;
    unsigned c0 = (i0 < N_NODES) ? cnt[i0] : 0;
    unsigned c1 = (i0 + 1 < N_NODES) ? cnt[i0 + 1] : 0;
    unsigned s = c0 + c1;
    tmp[t] = s; __syncthreads();
    for (int off = 1; off < 256; off <<= 1) {
        unsigned add = (t >= off) ? tmp[t - off] : 0;
        __syncthreads();
        tmp[t] += add;
        __syncthreads();
    }
    unsigned excl = tmp[t] - s;
    unsigned bb = bsum[blockIdx.x];
    if (i0 < N_NODES) rowptr[i0] = bb + excl;
    if (i0 + 1 < N_NODES) rowptr[i0 + 1] = bb + excl + c0;
}

__global__ void k_scatter(const int* __restrict__ src, const int* __restrict__ dst,
                          unsigned* __restrict__ cursor, unsigned* __restrict__ srcs) {
    int e = blockIdx.x * 256 + threadIdx.x;
    if (e < N_EDGES) {
        unsigned p = atomicAdd(&cursor[dst[e]], 1u);
        srcs[p] = (unsigned)src[e];
    }
}

// ---------------- mean aggregation (one wave per node) ----------------

__global__ __launch_bounds__(256) void k_aggregate(const float* __restrict__ h,
                                                   const unsigned* __restrict__ rowptr,
                                                   const unsigned* __restrict__ srcs,
                                                   float* __restrict__ agg) {
    int wave = threadIdx.x >> 6;
    int lane = threadIdx.x & 63;
    int node = blockIdx.x * 4 + wave;
    if (node >= N_NODES) return;
    unsigned b = rowptr[node], e = rowptr[node + 1];
    float a0 = 0.f, a1 = 0.f, b0 = 0.f, b1 = 0.f;
    unsigned i = b;
    for (; i + 2 <= e; i += 2) {
        unsigned s0 = srcs[i], s1 = srcs[i + 1];
        const float* p0 = h + (size_t)s0 * NF;
        const float* p1 = h + (size_t)s1 * NF;
        a0 += p0[lane]; a1 += p0[lane + 64];
        b0 += p1[lane]; b1 += p1[lane + 64];
    }
    if (i < e) {
        unsigned s = srcs[i];
        const float* p = h + (size_t)s * NF;
        a0 += p[lane]; a1 += p[lane + 64];
    }
    float sc = 1.f / fmaxf((float)(e - b), 1.f);
    agg[(size_t)node * NF + lane] = (a0 + b0) * sc;
    agg[(size_t)node * NF + 64 + lane] = (a1 + b1) * sc;
}

// ---------------- fused GEMM: out = act(A1@W1.T [+ A2@W2.T] + bias) ----------------
// 32 rows/block, 256 threads: thread (c = t&63, g = t>>6) computes rows g*8..g*8+7,
// cols c and c+64.

template <int HAS2, int RELU>
__global__ __launch_bounds__(256) void k_gemm128(const float* __restrict__ A1,
                                                 const float* __restrict__ W1,
                                                 const float* __restrict__ A2,
                                                 const float* __restrict__ W2,
                                                 const float* __restrict__ bias,
                                                 float* __restrict__ out, int nrows) {
    __shared__ float4 As[32][32];  // 32 rows x 128 floats
    const int t = threadIdx.x;
    const int c = t & 63;
    const int g = t >> 6;
    const int row0 = blockIdx.x * 32;
    float acc0[8], acc1[8];
#pragma unroll
    for (int i = 0; i < 8; ++i) { acc0[i] = 0.f; acc1[i] = 0.f; }

    const int npass = HAS2 ? 2 : 1;
    for (int pass = 0; pass < npass; ++pass) {
        const float* A = pass ? A2 : A1;
        const float* W = pass ? W2 : W1;
        if (pass) __syncthreads();
        // stage 32 rows (1024 float4, 4 per thread)
#pragma unroll
        for (int i = 0; i < 4; ++i) {
            int idx = t + i * 256;
            int r = idx >> 5, q = idx & 31;
            int gr = row0 + r;
            As[r][q] = (gr < nrows) ? ((const float4*)(A + (size_t)gr * NF))[q]
                                    : make_float4(0.f, 0.f, 0.f, 0.f);
        }
        __syncthreads();
        const float4* w0 = (const float4*)(W + (size_t)c * NF);
        const float4* w1 = (const float4*)(W + (size_t)(c + 64) * NF);
        for (int k4 = 0; k4 < 32; ++k4) {
            float4 wa = w0[k4];
            float4 wb = w1[k4];
#pragma unroll
            for (int i = 0; i < 8; ++i) {
                float4 av = As[g * 8 + i][k4];
                acc0[i] += av.x * wa.x + av.y * wa.y + av.z * wa.z + av.w * wa.w;
                acc1[i] += av.x * wb.x + av.y * wb.y + av.z * wb.z + av.w * wb.w;
            }
        }
    }
    float ba = bias[c], bb = bias[c + 64];
#pragma unroll
    for (int i = 0; i < 8; ++i) {
        int r = row0 + g * 8 + i;
        if (r < nrows) {
            float v0 = acc0[i] + ba;
            float v1 = acc1[i] + bb;
            if (RELU) { v0 = fmaxf(v0, 0.f); v1 = fmaxf(v1, 0.f); }
            out[(size_t)r * NF + c] = v0;
            out[(size_t)r * NF + 64 + c] = v1;
        }
    }
}

// ---------------- post-linear + log_softmax, blocked GEMM style ----------------
// 32 nodes/block, 256 threads. Thread (c = t&63, g = t>>6) computes rows
// g*8..g*8+7, class c (active for c < 40). Log-softmax fused: wave g owns all
// 40 classes of its 8 rows across lanes -> shuffle reduce.

__global__ __launch_bounds__(256) void k_post(const float* __restrict__ h,
                                              const float* __restrict__ Wp,
                                              const float* __restrict__ bp,
                                              float* __restrict__ out) {
    __shared__ float4 As[32][32];  // 32 rows x 128 floats
    const int t = threadIdx.x;
    const int c = t & 63;
    const int g = t >> 6;
    const int row0 = blockIdx.x * 32;
#pragma unroll
    for (int i = 0; i < 4; ++i) {
        int idx = t + i * 256;
        int r = idx >> 5, q = idx & 31;
        int gr = row0 + r;
        As[r][q] = (gr < N_NODES) ? ((const float4*)(h + (size_t)gr * NF))[q]
                                  : make_float4(0.f, 0.f, 0.f, 0.f);
    }
    __syncthreads();
    float acc[8];
    if (c < NC) {
        const float4* wp = (const float4*)(Wp + (size_t)c * NF);
        float bb = bp[c];
#pragma unroll
        for (int i = 0; i < 8; ++i) acc[i] = bb;
        for (int k4 = 0; k4 < 32; ++k4) {
            float4 wa = wp[k4];
#pragma unroll
            for (int i = 0; i < 8; ++i) {
                float4 av = As[g * 8 + i][k4];
                acc[i] += av.x * wa.x + av.y * wa.y + av.z * wa.z + av.w * wa.w;
            }
        }
    } else {
#pragma unroll
        for (int i = 0; i < 8; ++i) acc[i] = -INFINITY;
    }
#pragma unroll
    for (int i = 0; i < 8; ++i) {
        float v = acc[i];
        float m = v;
        for (int off = 32; off; off >>= 1) m = fmaxf(m, __shfl_xor(m, off, 64));
        float p = (c < NC) ? expf(v - m) : 0.f;
        float s = p;
        for (int off = 32; off; off >>= 1) s += __shfl_xor(s, off, 64);
        if (c < NC) {
            int r = row0 + g * 8 + i;
            if (r < N_NODES) out[(size_t)r * NC + c] = v - m - logf(s);
        }
    }
}

// ---------------- launch ----------------

extern "C" void kernel_launch(void* const* d_in, const int* in_sizes, int n_in,
                              void* d_out, int out_size, void* d_ws, size_t ws_size,
                              hipStream_t stream) {
    const float* x      = (const float*)d_in[0];
    const int*   ei     = (const int*)d_in[1];
    const float* W_pre  = (const float*)d_in[2];
    const float* b_pre  = (const float*)d_in[3];
    const float* Wl0    = (const float*)d_in[4];
    const float* bl0    = (const float*)d_in[5];
    const float* Wr0    = (const float*)d_in[6];
    const float* Wl1    = (const float*)d_in[7];
    const float* bl1    = (const float*)d_in[8];
    const float* Wr1    = (const float*)d_in[9];
    const float* W_post = (const float*)d_in[10];
    const float* b_post = (const float*)d_in[11];
    const int* src = ei;
    const int* dst = ei + N_EDGES;

    char* w = (char*)d_ws;
    float* h0  = (float*)w; w += (size_t)N_NODES * NF * 4;   // 51.2 MB (reused for h2)
    float* h1  = (float*)w; w += (size_t)N_NODES * NF * 4;
    float* agg = (float*)w; w += (size_t)N_NODES * NF * 4;
    unsigned* cnt    = (unsigned*)w; w += (size_t)(N_NODES + 32) * 4;
    unsigned* rowptr = (unsigned*)w; w += (size_t)(N_NODES + 32) * 4;
    unsigned* cursor = (unsigned*)w; w += (size_t)(N_NODES + 32) * 4;
    unsigned* bsum   = (unsigned*)w; w += 256 * 4;
    unsigned* srcs   = (unsigned*)w; w += (size_t)N_EDGES * 4;
    float* h2 = h0;

    float* outp = (float*)d_out;

    // CSR build (per call; deterministic work)
    hipMemsetAsync(cnt, 0, (size_t)N_NODES * 4, stream);
    k_degree<<<(N_EDGES + 255) / 256, 256, 0, stream>>>(dst, cnt);
    k_scanA<<<SCAN_BLOCKS, 256, 0, stream>>>(cnt, bsum);
    k_scanB<<<1, 256, 0, stream>>>(bsum, rowptr);
    k_scanC<<<SCAN_BLOCKS, 256, 0, stream>>>(cnt, bsum, rowptr);
    hipMemcpyAsync(cursor, rowptr, (size_t)N_NODES * 4, hipMemcpyDeviceToDevice, stream);
    k_scatter<<<(N_EDGES + 255) / 256, 256, 0, stream>>>(src, dst, cursor, srcs);

    const int gemm_grid = (N_NODES + 31) / 32;   // 3125 blocks, 32 rows each
    const int node_grid = (N_NODES + 3) / 4;     // for per-wave-per-node kernels

    // pre-linear
    k_gemm128<0, 0><<<gemm_grid, 256, 0, stream>>>(x, W_pre, nullptr, nullptr, b_pre, h0, N_NODES);
    // conv0
    k_aggregate<<<node_grid, 256, 0, stream>>>(h0, rowptr, srcs, agg);
    k_gemm128<1, 1><<<gemm_grid, 256, 0, stream>>>(agg, Wl0, h0, Wr0, bl0, h1, N_NODES);
    // conv1
    k_aggregate<<<node_grid, 256, 0, stream>>>(h1, rowptr, srcs, agg);
    k_gemm128<1, 1><<<gemm_grid, 256, 0, stream>>>(agg, Wl1, h1, Wr1, bl1, h2, N_NODES);
    // post + log_softmax  (32 nodes/block -> gemm_grid, NOT node_grid)
    k_post<<<gemm_grid, 256, 0, stream>>>(h2, W_post, b_post, outp);
}

// Round 4
// 642.582 us; speedup vs baseline: 2.0136x; 1.5842x over previous
//
#include <hip/hip_runtime.h>
#include <hip/hip_bf16.h>
#include <math.h>

#define N_NODES 100000
#define N_EDGES 1600000
#define NF 128
#define NC 40

#define SCAN_CHUNK 512
#define SCAN_BLOCKS ((N_NODES + SCAN_CHUNK - 1) / SCAN_CHUNK)  // 196

typedef __attribute__((ext_vector_type(8))) short short8v;   // 8 bf16 = 4 VGPRs
typedef __attribute__((ext_vector_type(4))) float f32x4;
typedef unsigned short ushort_t;

__device__ inline float bflo(unsigned v) { union { unsigned u; float f; } x; x.u = v << 16; return x.f; }
__device__ inline float bfhi(unsigned v) { union { unsigned u; float f; } x; x.u = v & 0xffff0000u; return x.f; }
__device__ inline ushort_t f2bf(float f) {
    __hip_bfloat16 h = __float2bfloat16(f);
    return __builtin_bit_cast(ushort_t, h);
}

// ---------------- CSR build ----------------

__global__ void k_degree(const int* __restrict__ dst, unsigned* __restrict__ cnt) {
    int e = blockIdx.x * 256 + threadIdx.x;
    if (e < N_EDGES) atomicAdd(&cnt[dst[e]], 1u);
}

__global__ void k_scanA(const unsigned* __restrict__ cnt, unsigned* __restrict__ bsum) {
    __shared__ unsigned red[256];
    int t = threadIdx.x;
    int i0 = blockIdx.x * SCAN_CHUNK + 2 * t;
    unsigned s = 0;
    if (i0 < N_NODES) s += cnt[i0];
    if (i0 + 1 < N_NODES) s += cnt[i0 + 1];
    red[t] = s; __syncthreads();
    for (int off = 128; off; off >>= 1) {
        if (t < off) red[t] += red[t + off];
        __syncthreads();
    }
    if (t == 0) bsum[blockIdx.x] = red[0];
}

__global__ void k_scanB(unsigned* bsum, unsigned* rowptr) {
    __shared__ unsigned tmp[256];
    int t = threadIdx.x;
    unsigned v = (t < SCAN_BLOCKS) ? bsum[t] : 0;
    tmp[t] = v; __syncthreads();
    for (int off = 1; off < 256; off <<= 1) {
        unsigned add = (t >= off) ? tmp[t - off] : 0;
        __syncthreads();
        tmp[t] += add;
        __syncthreads();
    }
    unsigned incl = tmp[t];
    if (t < SCAN_BLOCKS) bsum[t] = incl - v;   // exclusive
    if (t == 255) rowptr[N_NODES] = incl;      // total == N_EDGES
}

__global__ void k_scanC(const unsigned* __restrict__ cnt, const unsigned* __restrict__ bsum,
                        unsigned* __restrict__ rowptr) {
    __shared__ unsigned tmp[256];
    int t = threadIdx.x;
    int i0 = blockIdx.x * SCAN_CHUNK + 2 * t;
    unsigned c0 = (i0 < N_NODES) ? cnt[i0] : 0;
    unsigned c1 = (i0 + 1 < N_NODES) ? cnt[i0 + 1] : 0;
    unsigned s = c0 + c1;
    tmp[t] = s; __syncthreads();
    for (int off = 1; off < 256; off <<= 1) {
        unsigned add = (t >= off) ? tmp[t - off] : 0;
        __syncthreads();
        tmp[t] += add;
        __syncthreads();
    }
    unsigned excl = tmp[t] - s;
    unsigned bb = bsum[blockIdx.x];
    if (i0 < N_NODES) rowptr[i0] = bb + excl;
    if (i0 + 1 < N_NODES) rowptr[i0 + 1] = bb + excl + c0;
}

__global__ void k_scatter(const int* __restrict__ src, const int* __restrict__ dst,
                          unsigned* __restrict__ cursor, unsigned* __restrict__ srcs) {
    int e = blockIdx.x * 256 + threadIdx.x;
    if (e < N_EDGES) {
        unsigned p = atomicAdd(&cursor[dst[e]], 1u);
        srcs[p] = (unsigned)src[e];
    }
}

// ---------------- dtype casts ----------------

__global__ void k_castx(const float* __restrict__ x, ushort_t* __restrict__ xb) {
    int i = blockIdx.x * 256 + threadIdx.x;          // group of 4 elems
    if (i < N_NODES * NF / 4) {
        float4 v = ((const float4*)x)[i];
        ushort4 o;
        o.x = f2bf(v.x); o.y = f2bf(v.y); o.z = f2bf(v.z); o.w = f2bf(v.w);
        ((ushort4*)xb)[i] = o;
    }
}

__global__ void k_castw(const float* __restrict__ w0, const float* __restrict__ w1,
                        const float* __restrict__ w2, const float* __restrict__ w3,
                        const float* __restrict__ w4, ushort_t* __restrict__ out) {
    int i = blockIdx.x * 256 + threadIdx.x;          // 5 * 16384 total
    if (i < 5 * 16384) {
        int m = i >> 14, j = i & 16383;
        const float* s = (m == 0) ? w0 : (m == 1) ? w1 : (m == 2) ? w2 : (m == 3) ? w3 : w4;
        out[i] = f2bf(s[j]);
    }
}

// ---------------- mean aggregation (bf16 in/out, one wave per node) ----------------

__global__ __launch_bounds__(256) void k_aggregate(const ushort_t* __restrict__ h,
                                                   const unsigned* __restrict__ rowptr,
                                                   const unsigned* __restrict__ srcs,
                                                   ushort_t* __restrict__ agg) {
    int wave = threadIdx.x >> 6;
    int lane = threadIdx.x & 63;
    int node = blockIdx.x * 4 + wave;
    if (node >= N_NODES) return;
    unsigned b = rowptr[node], e = rowptr[node + 1];
    float a0 = 0.f, a1 = 0.f, b0 = 0.f, b1 = 0.f;
    unsigned i = b;
    for (; i + 2 <= e; i += 2) {
        unsigned s0 = srcs[i], s1 = srcs[i + 1];
        unsigned v0 = ((const unsigned*)(h + (size_t)s0 * NF))[lane];
        unsigned v1 = ((const unsigned*)(h + (size_t)s1 * NF))[lane];
        a0 += bflo(v0); a1 += bfhi(v0);
        b0 += bflo(v1); b1 += bfhi(v1);
    }
    if (i < e) {
        unsigned v0 = ((const unsigned*)(h + (size_t)srcs[i] * NF))[lane];
        a0 += bflo(v0); a1 += bfhi(v0);
    }
    float sc = 1.f / fmaxf((float)(e - b), 1.f);
    unsigned o = ((unsigned)f2bf((a1 + b1) * sc) << 16) | (unsigned)f2bf((a0 + b0) * sc);
    ((unsigned*)(agg + (size_t)node * NF))[lane] = o;
}

// ---------------- MFMA GEMM: out = act(A1@W1.T [+ A2@W2.T] + bias), bf16 ----------------
// 4 waves/block, wave w owns rows blockIdx.x*64 + w*16 .. +15, all 128 cols.
// Fragment layout (gfx950 16x16x32 bf16): A lane l -> row l&15, k = 8*(l>>4)+j (16B contig);
// B lane l -> col l&15, same k pattern (W is [outcol][k] row-major -> direct row reads);
// D lane l, reg r -> col l&15, row (l>>4)*4 + r  [m89-verified].

template <int HAS2, int RELU>
__global__ __launch_bounds__(256) void k_mfma_gemm(const ushort_t* __restrict__ A1,
                                                   const ushort_t* __restrict__ W1,
                                                   const ushort_t* __restrict__ A2,
                                                   const ushort_t* __restrict__ W2,
                                                   const float* __restrict__ bias,
                                                   ushort_t* __restrict__ out, int nrows) {
    const int lane = threadIdx.x & 63;
    const int wv = threadIdx.x >> 6;
    const int r0 = blockIdx.x * 64 + wv * 16;
    const int lr = lane & 15;
    const int kg = lane >> 4;

    int arow = r0 + lr;
    if (arow >= nrows) arow = nrows - 1;   // clamp; stores are guarded

    const short8v* a1p = (const short8v*)(A1 + (size_t)arow * NF + kg * 8);
    short8v af1[4], af2[4];
#pragma unroll
    for (int ks = 0; ks < 4; ++ks) af1[ks] = a1p[ks * 4];
    if (HAS2) {
        const short8v* a2p = (const short8v*)(A2 + (size_t)arow * NF + kg * 8);
#pragma unroll
        for (int ks = 0; ks < 4; ++ks) af2[ks] = a2p[ks * 4];
    }

    f32x4 acc[8];
#pragma unroll
    for (int ct = 0; ct < 8; ++ct) acc[ct] = (f32x4){0.f, 0.f, 0.f, 0.f};

#pragma unroll
    for (int ct = 0; ct < 8; ++ct) {
        const short8v* b1p = (const short8v*)(W1 + (size_t)(ct * 16 + lr) * NF + kg * 8);
#pragma unroll
        for (int ks = 0; ks < 4; ++ks)
            acc[ct] = __builtin_amdgcn_mfma_f32_16x16x32_bf16(af1[ks], b1p[ks * 4], acc[ct], 0, 0, 0);
        if (HAS2) {
            const short8v* b2p = (const short8v*)(W2 + (size_t)(ct * 16 + lr) * NF + kg * 8);
#pragma unroll
            for (int ks = 0; ks < 4; ++ks)
                acc[ct] = __builtin_amdgcn_mfma_f32_16x16x32_bf16(af2[ks], b2p[ks * 4], acc[ct], 0, 0, 0);
        }
    }

    const int orow0 = r0 + kg * 4;
#pragma unroll
    for (int ct = 0; ct < 8; ++ct) {
        float bv = bias[ct * 16 + lr];
#pragma unroll
        for (int r = 0; r < 4; ++r) {
            int row = orow0 + r;
            if (row < nrows) {
                float v = acc[ct][r] + bv;
                if (RELU) v = fmaxf(v, 0.f);
                out[(size_t)row * NF + ct * 16 + lr] = f2bf(v);
            }
        }
    }
}

// ---------------- post-linear + log_softmax (bf16 input, f32 out) ----------------
// 32 nodes/block. Thread (c = t&63, g = t>>6): rows g*8..g*8+7, class c (c < 40).

__global__ __launch_bounds__(256) void k_post(const ushort_t* __restrict__ h,
                                              const float* __restrict__ Wp,
                                              const float* __restrict__ bp,
                                              float* __restrict__ out) {
    __shared__ float4 As[32][32];  // 32 rows x 128 floats
    const int t = threadIdx.x;
    const int c = t & 63;
    const int g = t >> 6;
    const int row0 = blockIdx.x * 32;
#pragma unroll
    for (int i = 0; i < 2; ++i) {
        int idx = t + i * 256;          // 512 chunks of 8 bf16
        int r = idx >> 4, q = idx & 15;
        int gr = row0 + r;
        if (gr >= N_NODES) gr = N_NODES - 1;
        short8v v = ((const short8v*)(h + (size_t)gr * NF))[q];
        float4 lo, hi;
        lo.x = bflo((ushort_t)v[0]); lo.y = bflo((ushort_t)v[1]);
        lo.z = bflo((ushort_t)v[2]); lo.w = bflo((ushort_t)v[3]);
        hi.x = bflo((ushort_t)v[4]); hi.y = bflo((ushort_t)v[5]);
        hi.z = bflo((ushort_t)v[6]); hi.w = bflo((ushort_t)v[7]);
        As[r][q * 2] = lo; As[r][q * 2 + 1] = hi;
    }
    __syncthreads();
    float acc[8];
    if (c < NC) {
        const float4* wp = (const float4*)(Wp + (size_t)c * NF);
        float bb = bp[c];
#pragma unroll
        for (int i = 0; i < 8; ++i) acc[i] = bb;
        for (int k4 = 0; k4 < 32; ++k4) {
            float4 wa = wp[k4];
#pragma unroll
            for (int i = 0; i < 8; ++i) {
                float4 av = As[g * 8 + i][k4];
                acc[i] += av.x * wa.x + av.y * wa.y + av.z * wa.z + av.w * wa.w;
            }
        }
    } else {
#pragma unroll
        for (int i = 0; i < 8; ++i) acc[i] = -INFINITY;
    }
#pragma unroll
    for (int i = 0; i < 8; ++i) {
        float v = acc[i];
        float m = v;
        for (int off = 32; off; off >>= 1) m = fmaxf(m, __shfl_xor(m, off, 64));
        float p = (c < NC) ? expf(v - m) : 0.f;
        float s = p;
        for (int off = 32; off; off >>= 1) s += __shfl_xor(s, off, 64);
        if (c < NC) {
            int r = row0 + g * 8 + i;
            if (r < N_NODES) out[(size_t)r * NC + c] = v - m - logf(s);
        }
    }
}

// ---------------- launch ----------------

extern "C" void kernel_launch(void* const* d_in, const int* in_sizes, int n_in,
                              void* d_out, int out_size, void* d_ws, size_t ws_size,
                              hipStream_t stream) {
    const float* x      = (const float*)d_in[0];
    const int*   ei     = (const int*)d_in[1];
    const float* W_pre  = (const float*)d_in[2];
    const float* b_pre  = (const float*)d_in[3];
    const float* Wl0    = (const float*)d_in[4];
    const float* bl0    = (const float*)d_in[5];
    const float* Wr0    = (const float*)d_in[6];
    const float* Wl1    = (const float*)d_in[7];
    const float* bl1    = (const float*)d_in[8];
    const float* Wr1    = (const float*)d_in[9];
    const float* W_post = (const float*)d_in[10];
    const float* b_post = (const float*)d_in[11];
    const int* src = ei;
    const int* dst = ei + N_EDGES;

    const size_t act_bytes = (size_t)N_NODES * NF * 2;   // 25.6 MB
    char* w = (char*)d_ws;
    ushort_t* xb   = (ushort_t*)w; w += act_bytes;
    ushort_t* h0   = (ushort_t*)w; w += act_bytes;
    ushort_t* h1   = (ushort_t*)w; w += act_bytes;
    ushort_t* aggb = (ushort_t*)w; w += act_bytes;
    ushort_t* wb   = (ushort_t*)w; w += (size_t)5 * 16384 * 2;
    unsigned* cnt    = (unsigned*)w; w += (size_t)(N_NODES + 32) * 4;
    unsigned* rowptr = (unsigned*)w; w += (size_t)(N_NODES + 32) * 4;
    unsigned* cursor = (unsigned*)w; w += (size_t)(N_NODES + 32) * 4;
    unsigned* bsum   = (unsigned*)w; w += 256 * 4;
    unsigned* srcs   = (unsigned*)w; w += (size_t)N_EDGES * 4;
    ushort_t* h2 = h0;   // reuse

    ushort_t* wb_pre = wb;
    ushort_t* wb_l0  = wb + 16384;
    ushort_t* wb_r0  = wb + 2 * 16384;
    ushort_t* wb_l1  = wb + 3 * 16384;
    ushort_t* wb_r1  = wb + 4 * 16384;

    float* outp = (float*)d_out;

    // CSR build
    hipMemsetAsync(cnt, 0, (size_t)N_NODES * 4, stream);
    k_degree<<<(N_EDGES + 255) / 256, 256, 0, stream>>>(dst, cnt);
    k_scanA<<<SCAN_BLOCKS, 256, 0, stream>>>(cnt, bsum);
    k_scanB<<<1, 256, 0, stream>>>(bsum, rowptr);
    k_scanC<<<SCAN_BLOCKS, 256, 0, stream>>>(cnt, bsum, rowptr);
    hipMemcpyAsync(cursor, rowptr, (size_t)N_NODES * 4, hipMemcpyDeviceToDevice, stream);
    k_scatter<<<(N_EDGES + 255) / 256, 256, 0, stream>>>(src, dst, cursor, srcs);

    // casts
    k_castw<<<(5 * 16384 + 255) / 256, 256, 0, stream>>>(W_pre, Wl0, Wr0, Wl1, Wr1, wb);
    k_castx<<<(N_NODES * NF / 4 + 255) / 256, 256, 0, stream>>>(x, xb);

    const int mfma_grid = (N_NODES + 63) / 64;   // 1563
    const int post_grid = (N_NODES + 31) / 32;   // 3125
    const int node_grid = (N_NODES + 3) / 4;     // 25000

    // pre-linear
    k_mfma_gemm<0, 0><<<mfma_grid, 256, 0, stream>>>(xb, wb_pre, nullptr, nullptr, b_pre, h0, N_NODES);
    // conv0
    k_aggregate<<<node_grid, 256, 0, stream>>>(h0, rowptr, srcs, aggb);
    k_mfma_gemm<1, 1><<<mfma_grid, 256, 0, stream>>>(aggb, wb_l0, h0, wb_r0, bl0, h1, N_NODES);
    // conv1
    k_aggregate<<<node_grid, 256, 0, stream>>>(h1, rowptr, srcs, aggb);
    k_mfma_gemm<1, 1><<<mfma_grid, 256, 0, stream>>>(aggb, wb_l1, h1, wb_r1, bl1, h2, N_NODES);
    // post + log_softmax
    k_post<<<post_grid, 256, 0, stream>>>(h2, W_post, b_post, outp);
}

// Round 5
// 577.845 us; speedup vs baseline: 2.2392x; 1.1120x over previous
//
#include <hip/hip_runtime.h>
#include <hip/hip_bf16.h>
#include <math.h>

#define N_NODES 100000
#define N_EDGES 1600000
#define NF 128
#define NC 40

#define SCAN_CHUNK 512
#define SCAN_BLOCKS ((N_NODES + SCAN_CHUNK - 1) / SCAN_CHUNK)  // 196

// XCD-affine scatter geometry
#define SC_GROUPS 8
#define SC_NODES_PER_G ((N_NODES + SC_GROUPS - 1) / SC_GROUPS)   // 12500
#define SC_CHUNKS 256
#define SC_CHUNK_E ((N_EDGES + SC_CHUNKS - 1) / SC_CHUNKS)       // 6250

typedef __attribute__((ext_vector_type(8))) short short8v;   // 8 bf16 = 4 VGPRs
typedef __attribute__((ext_vector_type(4))) float f32x4;
typedef unsigned short ushort_t;

__device__ inline float bflo(unsigned v) { union { unsigned u; float f; } x; x.u = v << 16; return x.f; }
__device__ inline float bfhi(unsigned v) { union { unsigned u; float f; } x; x.u = v & 0xffff0000u; return x.f; }
__device__ inline ushort_t f2bf(float f) {
    __hip_bfloat16 h = __float2bfloat16(f);
    return __builtin_bit_cast(ushort_t, h);
}

// ---------------- CSR build ----------------

__global__ void k_degree(const int* __restrict__ dst, unsigned* __restrict__ cnt) {
    int e = blockIdx.x * 256 + threadIdx.x;
    if (e < N_EDGES) atomicAdd(&cnt[dst[e]], 1u);
}

__global__ void k_scanA(const unsigned* __restrict__ cnt, unsigned* __restrict__ bsum) {
    __shared__ unsigned red[256];
    int t = threadIdx.x;
    int i0 = blockIdx.x * SCAN_CHUNK + 2 * t;
    unsigned s = 0;
    if (i0 < N_NODES) s += cnt[i0];
    if (i0 + 1 < N_NODES) s += cnt[i0 + 1];
    red[t] = s; __syncthreads();
    for (int off = 128; off; off >>= 1) {
        if (t < off) red[t] += red[t + off];
        __syncthreads();
    }
    if (t == 0) bsum[blockIdx.x] = red[0];
}

__global__ void k_scanB(unsigned* bsum, unsigned* rowptr) {
    __shared__ unsigned tmp[256];
    int t = threadIdx.x;
    unsigned v = (t < SCAN_BLOCKS) ? bsum[t] : 0;
    tmp[t] = v; __syncthreads();
    for (int off = 1; off < 256; off <<= 1) {
        unsigned add = (t >= off) ? tmp[t - off] : 0;
        __syncthreads();
        tmp[t] += add;
        __syncthreads();
    }
    unsigned incl = tmp[t];
    if (t < SCAN_BLOCKS) bsum[t] = incl - v;   // exclusive
    if (t == 255) rowptr[N_NODES] = incl;      // total == N_EDGES
}

__global__ void k_scanC(const unsigned* __restrict__ cnt, const unsigned* __restrict__ bsum,
                        unsigned* __restrict__ rowptr) {
    __shared__ unsigned tmp[256];
    int t = threadIdx.x;
    int i0 = blockIdx.x * SCAN_CHUNK + 2 * t;
    unsigned c0 = (i0 < N_NODES) ? cnt[i0] : 0;
    unsigned c1 = (i0 + 1 < N_NODES) ? cnt[i0 + 1] : 0;
    unsigned s = c0 + c1;
    tmp[t] = s; __syncthreads();
    for (int off = 1; off < 256; off <<= 1) {
        unsigned add = (t >= off) ? tmp[t - off] : 0;
        __syncthreads();
        tmp[t] += add;
        __syncthreads();
    }
    unsigned excl = tmp[t] - s;
    unsigned bb = bsum[blockIdx.x];
    if (i0 < N_NODES) rowptr[i0] = bb + excl;
    if (i0 + 1 < N_NODES) rowptr[i0 + 1] = bb + excl + c0;
}

// XCD-affine scatter: group g = blockIdx&7 (round-robin XCD mapping) handles
// dst in [g*12500, (g+1)*12500). Each group scans all edges (dst reads are
// L3-resident) but its srcs/cursor write region (0.8 MB / 50 KB) stays in one
// XCD's L2 -> dense single writeback instead of 16x cross-XCD line ping-pong.

__global__ __launch_bounds__(256) void k_scatter8(const int* __restrict__ src,
                                                  const int* __restrict__ dst,
                                                  unsigned* __restrict__ cursor,
                                                  unsigned* __restrict__ srcs) {
    const unsigned g = blockIdx.x & (SC_GROUPS - 1);
    const int chunk = blockIdx.x >> 3;
    const unsigned gbase = g * SC_NODES_PER_G;
    int e0 = chunk * SC_CHUNK_E;
    int e1 = e0 + SC_CHUNK_E; if (e1 > N_EDGES) e1 = N_EDGES;
    for (int e = e0 + (int)threadIdx.x; e < e1; e += 256) {
        int d = dst[e];
        int s = src[e];
        if ((unsigned)(d - gbase) < (unsigned)SC_NODES_PER_G) {
            unsigned p = atomicAdd(&cursor[d], 1u);
            srcs[p] = (unsigned)s;
        }
    }
}

// ---------------- dtype casts ----------------

__global__ void k_castx(const float* __restrict__ x, ushort_t* __restrict__ xb) {
    int i = blockIdx.x * 256 + threadIdx.x;          // group of 4 elems
    if (i < N_NODES * NF / 4) {
        float4 v = ((const float4*)x)[i];
        ushort4 o;
        o.x = f2bf(v.x); o.y = f2bf(v.y); o.z = f2bf(v.z); o.w = f2bf(v.w);
        ((ushort4*)xb)[i] = o;
    }
}

__global__ void k_castw(const float* __restrict__ w0, const float* __restrict__ w1,
                        const float* __restrict__ w2, const float* __restrict__ w3,
                        const float* __restrict__ w4, ushort_t* __restrict__ out) {
    int i = blockIdx.x * 256 + threadIdx.x;          // 5 * 16384 total
    if (i < 5 * 16384) {
        int m = i >> 14, j = i & 16383;
        const float* s = (m == 0) ? w0 : (m == 1) ? w1 : (m == 2) ? w2 : (m == 3) ? w3 : w4;
        out[i] = f2bf(s[j]);
    }
}

// ---------------- mean aggregation (bf16 in/out, one wave per node) ----------------

__global__ __launch_bounds__(256) void k_aggregate(const ushort_t* __restrict__ h,
                                                   const unsigned* __restrict__ rowptr,
                                                   const unsigned* __restrict__ srcs,
                                                   ushort_t* __restrict__ agg) {
    int wave = threadIdx.x >> 6;
    int lane = threadIdx.x & 63;
    int node = blockIdx.x * 4 + wave;
    if (node >= N_NODES) return;
    unsigned b = rowptr[node], e = rowptr[node + 1];
    float a0 = 0.f, a1 = 0.f, b0 = 0.f, b1 = 0.f;
    unsigned i = b;
    for (; i + 2 <= e; i += 2) {
        unsigned s0 = srcs[i], s1 = srcs[i + 1];
        unsigned v0 = ((const unsigned*)(h + (size_t)s0 * NF))[lane];
        unsigned v1 = ((const unsigned*)(h + (size_t)s1 * NF))[lane];
        a0 += bflo(v0); a1 += bfhi(v0);
        b0 += bflo(v1); b1 += bfhi(v1);
    }
    if (i < e) {
        unsigned v0 = ((const unsigned*)(h + (size_t)srcs[i] * NF))[lane];
        a0 += bflo(v0); a1 += bfhi(v0);
    }
    float sc = 1.f / fmaxf((float)(e - b), 1.f);
    unsigned o = ((unsigned)f2bf((a1 + b1) * sc) << 16) | (unsigned)f2bf((a0 + b0) * sc);
    ((unsigned*)(agg + (size_t)node * NF))[lane] = o;
}

// ---------------- MFMA GEMM: out = act(A1@W1.T [+ A2@W2.T] + bias), bf16 ----------------
// 4 waves/block, wave w owns rows blockIdx.x*64 + w*16 .. +15, all 128 cols.
// Fragment layout (gfx950 16x16x32 bf16): A lane l -> row l&15, k = 8*(l>>4)+j (16B contig);
// B lane l -> col l&15, same k pattern (W is [outcol][k] row-major -> direct row reads);
// D lane l, reg r -> col l&15, row (l>>4)*4 + r  [m89-verified].

template <int HAS2, int RELU>
__global__ __launch_bounds__(256) void k_mfma_gemm(const ushort_t* __restrict__ A1,
                                                   const ushort_t* __restrict__ W1,
                                                   const ushort_t* __restrict__ A2,
                                                   const ushort_t* __restrict__ W2,
                                                   const float* __restrict__ bias,
                                                   ushort_t* __restrict__ out, int nrows) {
    const int lane = threadIdx.x & 63;
    const int wv = threadIdx.x >> 6;
    const int r0 = blockIdx.x * 64 + wv * 16;
    const int lr = lane & 15;
    const int kg = lane >> 4;

    int arow = r0 + lr;
    if (arow >= nrows) arow = nrows - 1;   // clamp; stores are guarded

    const short8v* a1p = (const short8v*)(A1 + (size_t)arow * NF + kg * 8);
    short8v af1[4], af2[4];
#pragma unroll
    for (int ks = 0; ks < 4; ++ks) af1[ks] = a1p[ks * 4];
    if (HAS2) {
        const short8v* a2p = (const short8v*)(A2 + (size_t)arow * NF + kg * 8);
#pragma unroll
        for (int ks = 0; ks < 4; ++ks) af2[ks] = a2p[ks * 4];
    }

    f32x4 acc[8];
#pragma unroll
    for (int ct = 0; ct < 8; ++ct) acc[ct] = (f32x4){0.f, 0.f, 0.f, 0.f};

#pragma unroll
    for (int ct = 0; ct < 8; ++ct) {
        const short8v* b1p = (const short8v*)(W1 + (size_t)(ct * 16 + lr) * NF + kg * 8);
#pragma unroll
        for (int ks = 0; ks < 4; ++ks)
            acc[ct] = __builtin_amdgcn_mfma_f32_16x16x32_bf16(af1[ks], b1p[ks * 4], acc[ct], 0, 0, 0);
        if (HAS2) {
            const short8v* b2p = (const short8v*)(W2 + (size_t)(ct * 16 + lr) * NF + kg * 8);
#pragma unroll
            for (int ks = 0; ks < 4; ++ks)
                acc[ct] = __builtin_amdgcn_mfma_f32_16x16x32_bf16(af2[ks], b2p[ks * 4], acc[ct], 0, 0, 0);
        }
    }

    const int orow0 = r0 + kg * 4;
#pragma unroll
    for (int ct = 0; ct < 8; ++ct) {
        float bv = bias[ct * 16 + lr];
#pragma unroll
        for (int r = 0; r < 4; ++r) {
            int row = orow0 + r;
            if (row < nrows) {
                float v = acc[ct][r] + bv;
                if (RELU) v = fmaxf(v, 0.f);
                out[(size_t)row * NF + ct * 16 + lr] = f2bf(v);
            }
        }
    }
}

// ---------------- post-linear + log_softmax (bf16 input, f32 out) ----------------
// 32 nodes/block. Thread (c = t&63, g = t>>6): rows g*8..g*8+7, class c (c < 40).

__global__ __launch_bounds__(256) void k_post(const ushort_t* __restrict__ h,
                                              const float* __restrict__ Wp,
                                              const float* __restrict__ bp,
                                              float* __restrict__ out) {
    __shared__ float4 As[32][32];  // 32 rows x 128 floats
    const int t = threadIdx.x;
    const int c = t & 63;
    const int g = t >> 6;
    const int row0 = blockIdx.x * 32;
#pragma unroll
    for (int i = 0; i < 2; ++i) {
        int idx = t + i * 256;          // 512 chunks of 8 bf16
        int r = idx >> 4, q = idx & 15;
        int gr = row0 + r;
        if (gr >= N_NODES) gr = N_NODES - 1;
        short8v v = ((const short8v*)(h + (size_t)gr * NF))[q];
        float4 lo, hi;
        lo.x = bflo((ushort_t)v[0]); lo.y = bflo((ushort_t)v[1]);
        lo.z = bflo((ushort_t)v[2]); lo.w = bflo((ushort_t)v[3]);
        hi.x = bflo((ushort_t)v[4]); hi.y = bflo((ushort_t)v[5]);
        hi.z = bflo((ushort_t)v[6]); hi.w = bflo((ushort_t)v[7]);
        As[r][q * 2] = lo; As[r][q * 2 + 1] = hi;
    }
    __syncthreads();
    float acc[8];
    if (c < NC) {
        const float4* wp = (const float4*)(Wp + (size_t)c * NF);
        float bb = bp[c];
#pragma unroll
        for (int i = 0; i < 8; ++i) acc[i] = bb;
        for (int k4 = 0; k4 < 32; ++k4) {
            float4 wa = wp[k4];
#pragma unroll
            for (int i = 0; i < 8; ++i) {
                float4 av = As[g * 8 + i][k4];
                acc[i] += av.x * wa.x + av.y * wa.y + av.z * wa.z + av.w * wa.w;
            }
        }
    } else {
#pragma unroll
        for (int i = 0; i < 8; ++i) acc[i] = -INFINITY;
    }
#pragma unroll
    for (int i = 0; i < 8; ++i) {
        float v = acc[i];
        float m = v;
        for (int off = 32; off; off >>= 1) m = fmaxf(m, __shfl_xor(m, off, 64));
        float p = (c < NC) ? expf(v - m) : 0.f;
        float s = p;
        for (int off = 32; off; off >>= 1) s += __shfl_xor(s, off, 64);
        if (c < NC) {
            int r = row0 + g * 8 + i;
            if (r < N_NODES) out[(size_t)r * NC + c] = v - m - logf(s);
        }
    }
}

// ---------------- launch ----------------

extern "C" void kernel_launch(void* const* d_in, const int* in_sizes, int n_in,
                              void* d_out, int out_size, void* d_ws, size_t ws_size,
                              hipStream_t stream) {
    const float* x      = (const float*)d_in[0];
    const int*   ei     = (const int*)d_in[1];
    const float* W_pre  = (const float*)d_in[2];
    const float* b_pre  = (const float*)d_in[3];
    const float* Wl0    = (const float*)d_in[4];
    const float* bl0    = (const float*)d_in[5];
    const float* Wr0    = (const float*)d_in[6];
    const float* Wl1    = (const float*)d_in[7];
    const float* bl1    = (const float*)d_in[8];
    const float* Wr1    = (const float*)d_in[9];
    const float* W_post = (const float*)d_in[10];
    const float* b_post = (const float*)d_in[11];
    const int* src = ei;
    const int* dst = ei + N_EDGES;

    const size_t act_bytes = (size_t)N_NODES * NF * 2;   // 25.6 MB
    char* w = (char*)d_ws;
    ushort_t* xb   = (ushort_t*)w; w += act_bytes;
    ushort_t* h0   = (ushort_t*)w; w += act_bytes;
    ushort_t* h1   = (ushort_t*)w; w += act_bytes;
    ushort_t* aggb = (ushort_t*)w; w += act_bytes;
    ushort_t* wb   = (ushort_t*)w; w += (size_t)5 * 16384 * 2;
    unsigned* cnt    = (unsigned*)w; w += (size_t)(N_NODES + 32) * 4;
    unsigned* rowptr = (unsigned*)w; w += (size_t)(N_NODES + 32) * 4;
    unsigned* cursor = (unsigned*)w; w += (size_t)(N_NODES + 32) * 4;
    unsigned* bsum   = (unsigned*)w; w += 256 * 4;
    unsigned* srcs   = (unsigned*)w; w += (size_t)N_EDGES * 4;
    ushort_t* h2 = h0;   // reuse

    ushort_t* wb_pre = wb;
    ushort_t* wb_l0  = wb + 16384;
    ushort_t* wb_r0  = wb + 2 * 16384;
    ushort_t* wb_l1  = wb + 3 * 16384;
    ushort_t* wb_r1  = wb + 4 * 16384;

    float* outp = (float*)d_out;

    // CSR build
    hipMemsetAsync(cnt, 0, (size_t)N_NODES * 4, stream);
    k_degree<<<(N_EDGES + 255) / 256, 256, 0, stream>>>(dst, cnt);
    k_scanA<<<SCAN_BLOCKS, 256, 0, stream>>>(cnt, bsum);
    k_scanB<<<1, 256, 0, stream>>>(bsum, rowptr);
    k_scanC<<<SCAN_BLOCKS, 256, 0, stream>>>(cnt, bsum, rowptr);
    hipMemcpyAsync(cursor, rowptr, (size_t)N_NODES * 4, hipMemcpyDeviceToDevice, stream);
    k_scatter8<<<SC_GROUPS * SC_CHUNKS, 256, 0, stream>>>(src, dst, cursor, srcs);

    // casts
    k_castw<<<(5 * 16384 + 255) / 256, 256, 0, stream>>>(W_pre, Wl0, Wr0, Wl1, Wr1, wb);
    k_castx<<<(N_NODES * NF / 4 + 255) / 256, 256, 0, stream>>>(x, xb);

    const int mfma_grid = (N_NODES + 63) / 64;   // 1563
    const int post_grid = (N_NODES + 31) / 32;   // 3125
    const int node_grid = (N_NODES + 3) / 4;     // 25000

    // pre-linear
    k_mfma_gemm<0, 0><<<mfma_grid, 256, 0, stream>>>(xb, wb_pre, nullptr, nullptr, b_pre, h0, N_NODES);
    // conv0
    k_aggregate<<<node_grid, 256, 0, stream>>>(h0, rowptr, srcs, aggb);
    k_mfma_gemm<1, 1><<<mfma_grid, 256, 0, stream>>>(aggb, wb_l0, h0, wb_r0, bl0, h1, N_NODES);
    // conv1
    k_aggregate<<<node_grid, 256, 0, stream>>>(h1, rowptr, srcs, aggb);
    k_mfma_gemm<1, 1><<<mfma_grid, 256, 0, stream>>>(aggb, wb_l1, h1, wb_r1, bl1, h2, N_NODES);
    // post + log_softmax
    k_post<<<post_grid, 256, 0, stream>>>(h2, W_post, b_post, outp);
}